// Round 10
// baseline (734.686 us; speedup 1.0000x reference)
//
#include <hip/hip_runtime.h>

// voltageNN R9: LSTM inner loop reverted to EXACT R4 form (proven 492us;
// R8's rcp-merge + CH=20 regressed to 620us -- at 1 wave/SIMD the step is
// exposed-latency-bound, not issue-bound, and more knife-edge boundaries
// compound through the layer pipeline). New in R9: the MLP head is folded
// into the SAME launch as 128 extra blocks (bid 640..767) that consume
// layer-4 chunks via the proven flag protocol, accumulating the W1 GEMV
// chunk-by-chunk in the spin slack (fully hidden under the LSTM); the
// second kernel launch and its ~40-70us tail disappear.

#define LAYERS 5
#define TT 1000
#define BATCH 128
#define CH 40            // chunk length (divides TT)
#define NCH (TT / CH)    // 25 chunks

#define LOG2E 1.4426950408889634f

__device__ __forceinline__ float fast_exp2(float x) {
#if __has_builtin(__builtin_amdgcn_exp2f)
  return __builtin_amdgcn_exp2f(x);
#else
  return __exp2f(x);
#endif
}
__device__ __forceinline__ float fast_rcp(float x) {
#if __has_builtin(__builtin_amdgcn_rcpf)
  return __builtin_amdgcn_rcpf(x);
#else
  return 1.0f / x;
#endif
}
// sigmoid for the MLP head (unscaled weights there)
__device__ __forceinline__ float fast_sigmoid(float z) {
  float e = fast_exp2(-LOG2E * z);
  return fast_rcp(1.0f + e);
}

template <int CTRL>
__device__ __forceinline__ float dpp_add(float v) {
  int moved = __builtin_amdgcn_update_dpp(0, __builtin_bit_cast(int, v),
                                          CTRL, 0xF, 0xF, false);
  return v + __builtin_bit_cast(float, moved);
}

// Wave64 total, returned wave-uniform (SGPR via readlane 63).
__device__ __forceinline__ float wave_sum_uniform(float v) {
  v = dpp_add<0x128>(v);  // row_ror:8
  v = dpp_add<0x124>(v);  // row_ror:4
  v = dpp_add<0x122>(v);  // row_ror:2
  v = dpp_add<0x121>(v);  // row_ror:1
  v = dpp_add<0x142>(v);  // row_bcast:15
  v = dpp_add<0x143>(v);  // row_bcast:31
  return __builtin_bit_cast(float, __builtin_amdgcn_readlane(__builtin_bit_cast(int, v), 63));
}

__device__ __forceinline__ float lane_bcast(float v, int s) {
  return __builtin_bit_cast(float, __builtin_amdgcn_readlane(__builtin_bit_cast(int, v), s));
}

__global__ __launch_bounds__(64) void lstm_fused_kernel(
    const float* __restrict__ x,     // [B, T]
    const float* __restrict__ Wih,   // [L, 1024]
    const float* __restrict__ Whh,   // [L, 1024]
    const float* __restrict__ bih,   // [L, 1024]
    const float* __restrict__ bhh,   // [L, 1024]
    const float* __restrict__ Whr,   // [L, 256]
    const float* __restrict__ W1, const float* __restrict__ b1,
    const float* __restrict__ W2, const float* __restrict__ b2,
    const float* __restrict__ W3, const float* __restrict__ b3,
    const float* __restrict__ W4, const float* __restrict__ b4,
    float* __restrict__ y,           // [B] final output
    float* __restrict__ seq,         // [L, B, T] layer outputs (workspace)
    int* __restrict__ flags)         // [L, B] chunk progress counters
{
  const int bid  = blockIdx.x;
  const int lane = threadIdx.x;

  if (bid < LAYERS * BATCH) {
    // ---------------- LSTM stage: EXACT R4 inner loop ----------------
    const int l = bid >> 7;   // bid / 128
    const int b = bid & 127;  // bid % 128

    // per-lane weights, pre-scaled into the exp2 domain.
    // gate order: 0=i, 1=f, 2=g(tanh), 3=o.  E[g] = exp2(sc*(pre-activation))
    // with sc = -log2e for sigmoid gates, -2log2e for the tanh gate.
    float wix[4][4], whx[4][4], gb[4][4], whr[4], cc[4];
    const int base = l * 1024;
#pragma unroll
    for (int g = 0; g < 4; ++g) {
      const float sc = (g == 2) ? (-2.0f * LOG2E) : (-LOG2E);
#pragma unroll
      for (int k = 0; k < 4; ++k) {
        int j = base + g * 256 + k * 64 + lane;
        wix[g][k] = Wih[j] * sc;
        whx[g][k] = Whh[j] * sc;
        gb[g][k]  = (bih[j] + bhh[j]) * sc;
      }
    }
#pragma unroll
    for (int k = 0; k < 4; ++k) {
      whr[k] = Whr[l * 256 + k * 64 + lane];
      cc[k] = 0.0f;
    }

    const float* in   = (l == 0) ? (x + b * TT) : (seq + ((l - 1) * BATCH + b) * TT);
    float*       outp = seq + (l * BATCH + b) * TT;
    int*       my_flag = flags + l * BATCH + b;
    const int* in_flag = (l > 0) ? (flags + (l - 1) * BATCH + b) : (const int*)flags;

    float h = 0.0f;
    for (int c = 0; c < NCH; ++c) {
      if (l > 0) {
        while (__hip_atomic_load(in_flag, __ATOMIC_ACQUIRE,
                                 __HIP_MEMORY_SCOPE_AGENT) <= c)
          __builtin_amdgcn_s_sleep(2);
      }
      float xv = 0.0f;
      if (lane < CH) {
        if (l == 0)
          xv = in[c * CH + lane];
        else
          xv = __hip_atomic_load(in + c * CH + lane, __ATOMIC_RELAXED,
                                 __HIP_MEMORY_SCOPE_AGENT);
      }

      float outv = 0.0f;
#pragma unroll 2
      for (int s = 0; s < CH; ++s) {
        const float xs = lane_bcast(xv, s);

        // phase A: h-independent part of all 16 pre-activations
        float gx[4][4];
#pragma unroll
        for (int g = 0; g < 4; ++g)
#pragma unroll
          for (int k = 0; k < 4; ++k)
            gx[g][k] = fmaf(xs, wix[g][k], gb[g][k]);

        // phase B+C: one fmaf from h, then exp2 (all 16 independent)
        float E[4][4];
#pragma unroll
        for (int g = 0; g < 4; ++g)
#pragma unroll
          for (int k = 0; k < 4; ++k)
            E[g][k] = fast_exp2(fmaf(h, whx[g][k], gx[g][k]));

        // phase D: gate combines, cell update, projection partial
        float r0, r1, r2, r3;
        {
          float rr[4];
#pragma unroll
          for (int k = 0; k < 4; ++k) {
            float ig = fast_rcp(1.0f + E[0][k]);
            float fg = fast_rcp(1.0f + E[1][k]);
            float gg = fmaf(2.0f, fast_rcp(1.0f + E[2][k]), -1.0f);
            float og = fast_rcp(1.0f + E[3][k]);
            cc[k] = fmaf(fg, cc[k], ig * gg);
            float tE = fast_exp2(cc[k] * (-2.0f * LOG2E));
            float tc = fmaf(2.0f, fast_rcp(1.0f + tE), -1.0f);
            rr[k] = og * tc * whr[k];
          }
          r0 = rr[0]; r1 = rr[1]; r2 = rr[2]; r3 = rr[3];
        }
        float r = (r0 + r1) + (r2 + r3);

        h = wave_sum_uniform(r);     // SGPR-uniform h(t)
        if (lane == s) outv = h;
      }

      // publish chunk (all layers, incl. l==4 which feeds the head blocks)
      if (lane < CH)
        __hip_atomic_store(outp + c * CH + lane, outv, __ATOMIC_RELAXED,
                           __HIP_MEMORY_SCOPE_AGENT);
      if (lane == 0)
        __hip_atomic_store(my_flag, c + 1, __ATOMIC_RELEASE,
                           __HIP_MEMORY_SCOPE_AGENT);
    }
    return;
  }

  // ---------------- MLP head stage (blocks 640..767, one per batch) --------
  __shared__ float sh[100];
  __shared__ float sh2[100];
  __shared__ float sh3[100];

  const int b = bid - LAYERS * BATCH;
  const int o0 = lane;        // output rows handled by this lane (lane<50)
  const int o1 = lane + 50;

  const int*   f4 = flags + 4 * BATCH + b;
  const float* h4 = seq + (4 * BATCH + b) * TT;

  // W1 GEMV accumulated chunk-by-chunk as layer-4 publishes (hidden in the
  // producer's ~17us/chunk slack).
  float acc0 = 0.0f, acc1 = 0.0f;
  for (int c = 0; c < NCH; ++c) {
    while (__hip_atomic_load(f4, __ATOMIC_ACQUIRE,
                             __HIP_MEMORY_SCOPE_AGENT) <= c)
      __builtin_amdgcn_s_sleep(8);
    // acquire-load invalidated L1 -> plain vector loads below see fresh data
    if (lane < 50) {
      const float* w0 = W1 + o0 * TT + c * CH;
      const float* w1 = W1 + o1 * TT + c * CH;
      const float* hh = h4 + c * CH;
#pragma unroll
      for (int t = 0; t < CH; t += 4) {
        float4 hv = *(const float4*)(hh + t);   // uniform across lanes
        float4 a  = *(const float4*)(w0 + t);
        float4 bq = *(const float4*)(w1 + t);
        acc0 = fmaf(a.x, hv.x, acc0);  acc1 = fmaf(bq.x, hv.x, acc1);
        acc0 = fmaf(a.y, hv.y, acc0);  acc1 = fmaf(bq.y, hv.y, acc1);
        acc0 = fmaf(a.z, hv.z, acc0);  acc1 = fmaf(bq.z, hv.z, acc1);
        acc0 = fmaf(a.w, hv.w, acc0);  acc1 = fmaf(bq.w, hv.w, acc1);
      }
    }
  }

  if (lane < 50) {
    sh[o0] = fast_sigmoid(acc0 + b1[o0]);
    sh[o1] = fast_sigmoid(acc1 + b1[o1]);
  }
  __syncthreads();

  // layer 2: [100 x 100] -> sigmoid
  if (lane < 50) {
    float a0 = b2[o0], a1 = b2[o1];
    const float* w0 = W2 + o0 * 100;
    const float* w1 = W2 + o1 * 100;
#pragma unroll 5
    for (int k = 0; k < 100; k += 4) {
      float4 v0 = *(const float4*)(w0 + k);
      float4 v1 = *(const float4*)(w1 + k);
      a0 = fmaf(v0.x, sh[k + 0], a0);  a1 = fmaf(v1.x, sh[k + 0], a1);
      a0 = fmaf(v0.y, sh[k + 1], a0);  a1 = fmaf(v1.y, sh[k + 1], a1);
      a0 = fmaf(v0.z, sh[k + 2], a0);  a1 = fmaf(v1.z, sh[k + 2], a1);
      a0 = fmaf(v0.w, sh[k + 3], a0);  a1 = fmaf(v1.w, sh[k + 3], a1);
    }
    sh2[o0] = fast_sigmoid(a0);
    sh2[o1] = fast_sigmoid(a1);
  }
  __syncthreads();

  // layer 3: [100 x 100] -> relu
  if (lane < 50) {
    float a0 = b3[o0], a1 = b3[o1];
    const float* w0 = W3 + o0 * 100;
    const float* w1 = W3 + o1 * 100;
#pragma unroll 5
    for (int k = 0; k < 100; k += 4) {
      float4 v0 = *(const float4*)(w0 + k);
      float4 v1 = *(const float4*)(w1 + k);
      a0 = fmaf(v0.x, sh2[k + 0], a0);  a1 = fmaf(v1.x, sh2[k + 0], a1);
      a0 = fmaf(v0.y, sh2[k + 1], a0);  a1 = fmaf(v1.y, sh2[k + 1], a1);
      a0 = fmaf(v0.z, sh2[k + 2], a0);  a1 = fmaf(v1.z, sh2[k + 2], a1);
      a0 = fmaf(v0.w, sh2[k + 3], a0);  a1 = fmaf(v1.w, sh2[k + 3], a1);
    }
    sh3[o0] = fmaxf(a0, 0.0f);
    sh3[o1] = fmaxf(a1, 0.0f);
  }
  __syncthreads();

  // layer 4: dot with W4 [1 x 100]
  float r = 0.0f;
  if (lane < 50) r = fmaf(sh3[o0], W4[o0], sh3[o1] * W4[o1]);
  r = wave_sum_uniform(r);
  if (lane == 0) y[b] = r + b4[0];
}

extern "C" void kernel_launch(void* const* d_in, const int* in_sizes, int n_in,
                              void* d_out, int out_size, void* d_ws, size_t ws_size,
                              hipStream_t stream) {
  const float* x   = (const float*)d_in[0];
  const float* Wih = (const float*)d_in[1];
  const float* Whh = (const float*)d_in[2];
  const float* bih = (const float*)d_in[3];
  const float* bhh = (const float*)d_in[4];
  const float* Whr = (const float*)d_in[5];
  const float* W1  = (const float*)d_in[6];
  const float* b1  = (const float*)d_in[7];
  const float* W2  = (const float*)d_in[8];
  const float* b2  = (const float*)d_in[9];
  const float* W3  = (const float*)d_in[10];
  const float* b3  = (const float*)d_in[11];
  const float* W4  = (const float*)d_in[12];
  const float* b4  = (const float*)d_in[13];

  float* seq   = (float*)d_ws;                       // [5][128][1000] f32 = 2.56 MB
  int*   flags = (int*)(seq + LAYERS * BATCH * TT);  // [5][128] int

  hipMemsetAsync(flags, 0, LAYERS * BATCH * sizeof(int), stream);
  lstm_fused_kernel<<<LAYERS * BATCH + BATCH, 64, 0, stream>>>(
      x, Wih, Whh, bih, bhh, Whr, W1, b1, W2, b2, W3, b3, W4, b4,
      (float*)d_out, seq, flags);
}

// Round 11
// 561.346 us; speedup vs baseline: 1.3088x; 1.3088x over previous
//
#include <hip/hip_runtime.h>

// voltageNN FINAL (= R4, the session optimum): decoupled wave-per-(layer,batch)
// pipeline. Six theory-driven deviations (R5-R9: cross-wave split, head fusion
// x2, rcp-merge, sentinel dataflow, CH=20) ALL regressed; counters showed
// dur x VALUBusy ~= const across variants -> fixed VALU work, variant-dependent
// stalls. Step time ~1018 cyc is dominated by trans-pipe occupancy (40 wave64
// exp2/rcp) + the serial DPP-reduce tail; no tested restructuring shortened it.
//   - cell computation phase-structured (gx fmafs | h fmafs | exp2s | rcps)
//   - weights pre-scaled by -log2e (i,f,o) / -2log2e (g): exp2 arg is ONE
//     fmaf away from h.
//   - allreduce: 4x row_ror + row_bcast15 + row_bcast31 DPP adds + readlane63.
//   - chunked (CH=40) acquire/release flag protocol between layers.

#define LAYERS 5
#define TT 1000
#define BATCH 128
#define CH 40            // chunk length (divides TT)
#define NCH (TT / CH)    // 25 chunks

#define LOG2E 1.4426950408889634f

__device__ __forceinline__ float fast_exp2(float x) {
#if __has_builtin(__builtin_amdgcn_exp2f)
  return __builtin_amdgcn_exp2f(x);
#else
  return __exp2f(x);
#endif
}
__device__ __forceinline__ float fast_rcp(float x) {
#if __has_builtin(__builtin_amdgcn_rcpf)
  return __builtin_amdgcn_rcpf(x);
#else
  return 1.0f / x;
#endif
}
// sigmoid for the MLP head (unscaled weights there)
__device__ __forceinline__ float fast_sigmoid(float z) {
  float e = fast_exp2(-LOG2E * z);
  return fast_rcp(1.0f + e);
}

template <int CTRL>
__device__ __forceinline__ float dpp_add(float v) {
  int moved = __builtin_amdgcn_update_dpp(0, __builtin_bit_cast(int, v),
                                          CTRL, 0xF, 0xF, false);
  return v + __builtin_bit_cast(float, moved);
}

// Wave64 total, returned wave-uniform (SGPR via readlane 63).
// row_ror 8/4/2/1 -> every lane holds its row-of-16 sum; row_bcast15 adds R0
// into row1 (R2 into row3); row_bcast31 adds (R0+R1) into rows 2,3 -> lanes
// 48..63 hold the full sum.
__device__ __forceinline__ float wave_sum_uniform(float v) {
  v = dpp_add<0x128>(v);  // row_ror:8
  v = dpp_add<0x124>(v);  // row_ror:4
  v = dpp_add<0x122>(v);  // row_ror:2
  v = dpp_add<0x121>(v);  // row_ror:1
  v = dpp_add<0x142>(v);  // row_bcast:15
  v = dpp_add<0x143>(v);  // row_bcast:31
  return __builtin_bit_cast(float, __builtin_amdgcn_readlane(__builtin_bit_cast(int, v), 63));
}

__device__ __forceinline__ float lane_bcast(float v, int s) {
  return __builtin_bit_cast(float, __builtin_amdgcn_readlane(__builtin_bit_cast(int, v), s));
}

__global__ __launch_bounds__(64) void lstm_wave_kernel(
    const float* __restrict__ x,     // [B, T]
    const float* __restrict__ Wih,   // [L, 1024]
    const float* __restrict__ Whh,   // [L, 1024]
    const float* __restrict__ bih,   // [L, 1024]
    const float* __restrict__ bhh,   // [L, 1024]
    const float* __restrict__ Whr,   // [L, 256]
    float* __restrict__ seq,         // [L, B, T] layer outputs (workspace)
    int* __restrict__ flags)         // [L, B] chunk progress counters
{
  const int bid  = blockIdx.x;
  const int l    = bid >> 7;   // bid / 128
  const int b    = bid & 127;  // bid % 128
  const int lane = threadIdx.x;

  // per-lane weights, pre-scaled into the exp2 domain.
  // gate order: 0=i, 1=f, 2=g(tanh), 3=o.  E[g] = exp2(sc*(pre-activation))
  // with sc = -log2e for sigmoid gates, -2log2e for the tanh gate.
  float wix[4][4], whx[4][4], gb[4][4], whr[4], cc[4];
  const int base = l * 1024;
#pragma unroll
  for (int g = 0; g < 4; ++g) {
    const float sc = (g == 2) ? (-2.0f * LOG2E) : (-LOG2E);
#pragma unroll
    for (int k = 0; k < 4; ++k) {
      int j = base + g * 256 + k * 64 + lane;
      wix[g][k] = Wih[j] * sc;
      whx[g][k] = Whh[j] * sc;
      gb[g][k]  = (bih[j] + bhh[j]) * sc;
    }
  }
#pragma unroll
  for (int k = 0; k < 4; ++k) {
    whr[k] = Whr[l * 256 + k * 64 + lane];
    cc[k] = 0.0f;
  }

  const float* in  = (l == 0) ? (x + b * TT) : (seq + ((l - 1) * BATCH + b) * TT);
  float*       out = seq + (l * BATCH + b) * TT;
  int*       my_flag = flags + l * BATCH + b;
  const int* in_flag = (l > 0) ? (flags + (l - 1) * BATCH + b) : (const int*)flags;

  float h = 0.0f;
  for (int c = 0; c < NCH; ++c) {
    if (l > 0) {
      while (__hip_atomic_load(in_flag, __ATOMIC_ACQUIRE,
                               __HIP_MEMORY_SCOPE_AGENT) <= c)
        __builtin_amdgcn_s_sleep(2);
    }
    float xv = 0.0f;
    if (lane < CH) {
      if (l == 0)
        xv = in[c * CH + lane];
      else
        xv = __hip_atomic_load(in + c * CH + lane, __ATOMIC_RELAXED,
                               __HIP_MEMORY_SCOPE_AGENT);
    }

    float outv = 0.0f;
#pragma unroll 2
    for (int s = 0; s < CH; ++s) {
      const float xs = lane_bcast(xv, s);

      // phase A: h-independent part of all 16 pre-activations
      float gx[4][4];
#pragma unroll
      for (int g = 0; g < 4; ++g)
#pragma unroll
        for (int k = 0; k < 4; ++k)
          gx[g][k] = fmaf(xs, wix[g][k], gb[g][k]);

      // phase B+C: one fmaf from h, then exp2 (all 16 independent)
      float E[4][4];
#pragma unroll
      for (int g = 0; g < 4; ++g)
#pragma unroll
        for (int k = 0; k < 4; ++k)
          E[g][k] = fast_exp2(fmaf(h, whx[g][k], gx[g][k]));

      // phase D: gate combines, cell update, projection partial (k's independent)
      float r0, r1, r2, r3;
      {
        float rr[4];
#pragma unroll
        for (int k = 0; k < 4; ++k) {
          float ig = fast_rcp(1.0f + E[0][k]);
          float fg = fast_rcp(1.0f + E[1][k]);
          float gg = fmaf(2.0f, fast_rcp(1.0f + E[2][k]), -1.0f);
          float og = fast_rcp(1.0f + E[3][k]);
          cc[k] = fmaf(fg, cc[k], ig * gg);
          float tE = fast_exp2(cc[k] * (-2.0f * LOG2E));
          float tc = fmaf(2.0f, fast_rcp(1.0f + tE), -1.0f);
          rr[k] = og * tc * whr[k];
        }
        r0 = rr[0]; r1 = rr[1]; r2 = rr[2]; r3 = rr[3];
      }
      float r = (r0 + r1) + (r2 + r3);

      h = wave_sum_uniform(r);     // SGPR-uniform h(t)
      if (lane == s) outv = h;
    }

    if (l < 4) {
      if (lane < CH)
        __hip_atomic_store(out + c * CH + lane, outv, __ATOMIC_RELAXED,
                           __HIP_MEMORY_SCOPE_AGENT);
      if (lane == 0)
        __hip_atomic_store(my_flag, c + 1, __ATOMIC_RELEASE,
                           __HIP_MEMORY_SCOPE_AGENT);
    } else {
      if (lane < CH) out[c * CH + lane] = outv;  // consumed by next launch
    }
  }
}

__global__ __launch_bounds__(256) void mlp_head_kernel(
    const float* __restrict__ seq4,  // [B, T] layer-4 outputs
    const float* __restrict__ W1, const float* __restrict__ b1,
    const float* __restrict__ W2, const float* __restrict__ b2,
    const float* __restrict__ W3, const float* __restrict__ b3,
    const float* __restrict__ W4, const float* __restrict__ b4,
    float* __restrict__ out)         // [B]
{
  __shared__ float sx[TT];
  __shared__ float sh[100];
  __shared__ float sh2[100];
  __shared__ float part[100];
  __shared__ float red[4];

  const int b = blockIdx.x, tid = threadIdx.x;
  for (int i = tid; i < TT; i += 256) sx[i] = seq4[b * TT + i];
  __syncthreads();

  // phase 1: 2 threads per output (tid<100: t in [0,500); tid in [128,228): [500,1000))
  const int half = (tid >= 128) ? 1 : 0;
  const int oid  = half ? (tid - 128) : tid;
  float myacc = 0.0f;
  if (oid < 100) {
    const float* w  = W1 + oid * TT + half * 500;
    const float* xx = sx + half * 500;
    float a0 = 0.f, a1 = 0.f, a2 = 0.f, a3 = 0.f;
    for (int t0 = 0; t0 < 500; t0 += 4) {
      float4 v = *(const float4*)(w + t0);
      a0 = fmaf(v.x, xx[t0 + 0], a0);
      a1 = fmaf(v.y, xx[t0 + 1], a1);
      a2 = fmaf(v.z, xx[t0 + 2], a2);
      a3 = fmaf(v.w, xx[t0 + 3], a3);
    }
    myacc = (a0 + a1) + (a2 + a3);
    if (half) part[oid] = myacc;
  }
  __syncthreads();
  if (tid < 100) sh[tid] = fast_sigmoid(myacc + part[tid] + b1[tid]);
  __syncthreads();

  if (tid < 100) {
    float acc = b2[tid];
    const float* w = W2 + tid * 100;
    for (int k = 0; k < 100; ++k) acc += w[k] * sh[k];
    sh2[tid] = fast_sigmoid(acc);
  }
  __syncthreads();

  if (tid < 100) {
    float acc = b3[tid];
    const float* w = W3 + tid * 100;
    for (int k = 0; k < 100; ++k) acc += w[k] * sh2[k];
    sh[tid] = fmaxf(acc, 0.0f);
  }
  __syncthreads();

  float r = (tid < 100) ? sh[tid] * W4[tid] : 0.0f;
  {  // wave sum (any-lane result on lane floor; use bcast path)
    r = dpp_add<0x128>(r);
    r = dpp_add<0x124>(r);
    r = dpp_add<0x122>(r);
    r = dpp_add<0x121>(r);
    r = dpp_add<0x142>(r);
    r = dpp_add<0x143>(r);
    r = __builtin_bit_cast(float, __builtin_amdgcn_readlane(__builtin_bit_cast(int, r), 63));
  }
  if ((tid & 63) == 0) red[tid >> 6] = r;
  __syncthreads();
  if (tid == 0) out[b] = (red[0] + red[1]) + (red[2] + red[3]) + b4[0];
}

extern "C" void kernel_launch(void* const* d_in, const int* in_sizes, int n_in,
                              void* d_out, int out_size, void* d_ws, size_t ws_size,
                              hipStream_t stream) {
  const float* x   = (const float*)d_in[0];
  const float* Wih = (const float*)d_in[1];
  const float* Whh = (const float*)d_in[2];
  const float* bih = (const float*)d_in[3];
  const float* bhh = (const float*)d_in[4];
  const float* Whr = (const float*)d_in[5];
  const float* W1  = (const float*)d_in[6];
  const float* b1  = (const float*)d_in[7];
  const float* W2  = (const float*)d_in[8];
  const float* b2  = (const float*)d_in[9];
  const float* W3  = (const float*)d_in[10];
  const float* b3  = (const float*)d_in[11];
  const float* W4  = (const float*)d_in[12];
  const float* b4  = (const float*)d_in[13];

  float* seq   = (float*)d_ws;                       // [5][128][1000] f32 = 2.56 MB
  int*   flags = (int*)(seq + LAYERS * BATCH * TT);  // [5][128] int

  hipMemsetAsync(flags, 0, LAYERS * BATCH * sizeof(int), stream);
  lstm_wave_kernel<<<LAYERS * BATCH, 64, 0, stream>>>(x, Wih, Whh, bih, bhh, Whr,
                                                      seq, flags);
  mlp_head_kernel<<<BATCH, 256, 0, stream>>>(seq + 4 * BATCH * TT,
                                             W1, b1, W2, b2, W3, b3, W4, b4,
                                             (float*)d_out);
}